// Round 3
// baseline (461.688 us; speedup 1.0000x reference)
//
#include <hip/hip_runtime.h>

// CNOT permutation on a batch of 2^n-amplitude state vectors (float32).
// out[b, j] = in[b, j ^ (1<<t2)]  if ((j >> c2) & 1)  else  in[b, j]
// with c2 = n - control - 1, t2 = n - target - 1.
//
// The batch stride is 2^n and c2,t2 < n, so the bit test/flip applies
// directly to the FLAT index. For c2,t2 >= 2 the permutation moves aligned
// groups of >=4 floats, so we gather whole float4s; both streams stay fully
// coalesced (the XOR only flips a high address bit).
//
// R1 -> R2: 452 us = 4.75 TB/s effective, vs 6.3-6.7 TB/s ceiling seen by
// the harness memsets on the same run. Fix ILP (1 dependent load->store per
// iter) with a 4x unroll (4 outstanding loads/wave), and use non-temporal
// load/store (pure stream, zero reuse, working set >> L3).

typedef float v4f __attribute__((ext_vector_type(4)));

__global__ __launch_bounds__(256) void
cnot_kernel(const v4f* __restrict__ in, v4f* __restrict__ out,
            const int* __restrict__ ctrl_p, const int* __restrict__ tgt_p,
            const int* __restrict__ nq_p, unsigned int n_vec) {
  const int n  = nq_p[0];
  const int c2 = n - ctrl_p[0] - 1;
  const int t2 = n - tgt_p[0] - 1;

  const unsigned int tid    = blockIdx.x * blockDim.x + threadIdx.x;
  const unsigned int stride = gridDim.x * blockDim.x;

  if (c2 >= 2 && t2 >= 2) {
    // Vectorized path (benched config: c2=20, t2=13).
    const unsigned int cmask = 1u << (c2 - 2);  // control bit, float4 units
    const unsigned int tmask = 1u << (t2 - 2);  // target flip, float4 units

    unsigned int i = tid;
    const unsigned int stride4 = stride * 4u;

    // Main loop: 4 independent loads in flight, then 4 stores.
    for (; i + 3u * stride < n_vec; i += stride4) {
      const unsigned int i0 = i;
      const unsigned int i1 = i +      stride;
      const unsigned int i2 = i + 2u * stride;
      const unsigned int i3 = i + 3u * stride;
      const unsigned int s0 = (i0 & cmask) ? (i0 ^ tmask) : i0;
      const unsigned int s1 = (i1 & cmask) ? (i1 ^ tmask) : i1;
      const unsigned int s2 = (i2 & cmask) ? (i2 ^ tmask) : i2;
      const unsigned int s3 = (i3 & cmask) ? (i3 ^ tmask) : i3;
      const v4f v0 = __builtin_nontemporal_load(&in[s0]);
      const v4f v1 = __builtin_nontemporal_load(&in[s1]);
      const v4f v2 = __builtin_nontemporal_load(&in[s2]);
      const v4f v3 = __builtin_nontemporal_load(&in[s3]);
      __builtin_nontemporal_store(v0, &out[i0]);
      __builtin_nontemporal_store(v1, &out[i1]);
      __builtin_nontemporal_store(v2, &out[i2]);
      __builtin_nontemporal_store(v3, &out[i3]);
    }
    // Tail (not taken when n_vec % (4*stride) == 0, as in the benched shape).
    for (; i < n_vec; i += stride) {
      const unsigned int src = (i & cmask) ? (i ^ tmask) : i;
      __builtin_nontemporal_store(__builtin_nontemporal_load(&in[src]), &out[i]);
    }
  } else {
    // Scalar fallback (correctness only; not expected to run here).
    const float* inf  = (const float*)in;
    float*       outf = (float*)out;
    const unsigned int cm = 1u << c2;
    const unsigned int tm = 1u << t2;
    const unsigned int n_el = n_vec * 4u;
    for (unsigned int e = tid; e < n_el; e += stride) {
      const unsigned int src = (e & cm) ? (e ^ tm) : e;
      outf[e] = inf[src];
    }
  }
}

extern "C" void kernel_launch(void* const* d_in, const int* in_sizes, int n_in,
                              void* d_out, int out_size, void* d_ws, size_t ws_size,
                              hipStream_t stream) {
  const float* state = (const float*)d_in[0];
  const int* control = (const int*)d_in[1];
  const int* target  = (const int*)d_in[2];
  const int* nq      = (const int*)d_in[3];
  float* out = (float*)d_out;

  const unsigned int n_el  = (unsigned int)in_sizes[0];  // 16 * 2^24 = 2^28
  const unsigned int n_vec = n_el / 4u;                  // 2^26 float4s

  dim3 block(256);
  dim3 grid(2048);  // 256 CU x 8 blocks -> 8 waves/SIMD; grid-stride covers rest
  hipLaunchKernelGGL(cnot_kernel, grid, block, 0, stream,
                     (const v4f*)state, (v4f*)out,
                     control, target, nq, n_vec);
}